// Round 13
// baseline (97.287 us; speedup 1.0000x reference)
//
#include <hip/hip_runtime.h>
#include <hip/hip_bf16.h>

// C = triu( triu(A) @ triu(B) ), N=4096, fp32 in/out.
// Pass 1 (prep): zero strictly-lower tiles of C + convert fp32->bf16 into
// TILED FRAGMENT-ORDER subtiles in d_ws.
// Pass 2 (main): 1000 blocks. Tiles with L<=8 k-tiles: one block, direct
// masked store (chain <=32 steps). Tiles with L>=9: ceil(L/8) chunk-blocks
// (<=32 steps each) writing fp32 PARTIAL tiles to d_ws (plain stores, no
// atomics). 3-buffer LDS pipeline + counted vmcnt(4), global_load_lds
// staging from fragment-ordered ws.
// Pass 3 (reduce): 300 blocks, sum each split tile's partials -> C.
// Deterministic, replay-safe (ws fully rewritten each call).

#define NDIM 4096
#define NBLK 32
#define SUBT_B 8192                        // one 128x32 bf16 subtile
#define NSUBT 2112                         // packed subtiles per matrix
#define WS_A ((size_t)NSUBT * SUBT_B)      // 17,301,504
#define WS_TOTAL (2 * WS_A)                // 34,603,008 (bf16 region)
#define NZERO 496                          // strictly-lower 128x128 tiles
#define NSPLIT 772                         // chunk-blocks (L>=9)
#define NMAIN 1000                         // 772 split + 228 direct
#define NRED 300                           // split tiles
#define PART_F 16384                       // floats per partial tile
#define WS_FULL (WS_TOTAL + (size_t)NSPLIT * PART_F * 4)   // 85,196,800

typedef __attribute__((ext_vector_type(8))) short short8;
typedef __attribute__((ext_vector_type(4))) float f32x4;

__device__ __forceinline__ unsigned pkbf(float a, float b) {
    __hip_bfloat162 h = __float22bfloat162_rn(make_float2(a, b));
    unsigned r;
    __builtin_memcpy(&r, &h, sizeof(r));
    return r;
}

__device__ __forceinline__ void gll16(const void* g, void* l) {
    __builtin_amdgcn_global_load_lds(
        (const __attribute__((address_space(1))) unsigned int*)g,
        (__attribute__((address_space(3))) unsigned int*)l, 16, 0, 0);
}

__device__ __forceinline__ int offA(int bi) { return 130 * bi - 2 * bi * bi; }
__device__ __forceinline__ int offB(int bj) { return 2 * bj * (bj + 1); }

// ---------------- pass 1: zero lower tiles + convert/tile A and B ----------
__global__ __launch_bounds__(256) void prep_kernel(
    const float* __restrict__ A, const float* __restrict__ B,
    float* __restrict__ C, char* __restrict__ ws) {
    const int t = threadIdx.x;
    int b = blockIdx.x;

    if (b < NZERO) {  // ---- zero one strictly-lower 128x128 tile ----
        int r = b, p = 1;
        while (r >= p) { r -= p; ++p; }
        const int bi = p, bj = r;          // bj < bi
        const size_t base = (size_t)bi * 128 * NDIM + (size_t)bj * 128;
        const float4 z = make_float4(0.f, 0.f, 0.f, 0.f);
#pragma unroll
        for (int j = 0; j < 16; ++j) {
            const int f = t + 256 * j;
            *reinterpret_cast<float4*>(
                &C[base + (size_t)(f >> 5) * NDIM + (f & 31) * 4]) = z;
        }
        return;
    }
    b -= NZERO;

    if (b < NSUBT) {  // ---- A subtile: [row][k] fp32 -> [g][row][16B] bf16 ----
        int bi = 0, rem = b;
        while (rem >= 128 - 4 * bi) { rem -= 128 - 4 * bi; ++bi; }
        const int kt32 = 4 * bi + rem;

        __shared__ __align__(16) char lsub[SUBT_B];
        const float* src = A + (size_t)(bi * 128) * NDIM + kt32 * 32;
#pragma unroll
        for (int j = 0; j < 4; ++j) {
            const int s4 = t + 256 * j;
            const int row = s4 >> 3;
            const int kf = (s4 & 7) * 4;
            const float4 v =
                *reinterpret_cast<const float4*>(src + (size_t)row * NDIM + kf);
            uint2 w;
            w.x = pkbf(v.x, v.y);
            w.y = pkbf(v.z, v.w);
            *reinterpret_cast<uint2*>(lsub + (kf >> 3) * 2048 + row * 16 +
                                      (kf & 4) * 2) = w;
        }
        __syncthreads();
        char* dst = ws + (size_t)b * SUBT_B;
#pragma unroll
        for (int j = 0; j < 2; ++j) {
            const int d = t + 256 * j;
            *reinterpret_cast<uint4*>(dst + d * 16) =
                *reinterpret_cast<const uint4*>(lsub + d * 16);
        }
        return;
    }
    b -= NSUBT;

    {  // ---- B subtile: transpose [k][col] fp32 -> [g][col][16B] bf16 ----
        int bj = 0, rem = b;
        while (rem >= 4 * (bj + 1)) { rem -= 4 * (bj + 1); ++bj; }
        const int kt32 = rem;

        const int c = t & 127;
        const int kq = (t >> 7) * 16;
        const float* src = B + (size_t)(kt32 * 32 + kq) * NDIM + bj * 128 + c;
        float v[16];
#pragma unroll
        for (int i = 0; i < 16; ++i) v[i] = src[(size_t)i * NDIM];

        uint4 w0, w1;
        w0.x = pkbf(v[0], v[1]);   w0.y = pkbf(v[2], v[3]);
        w0.z = pkbf(v[4], v[5]);   w0.w = pkbf(v[6], v[7]);
        w1.x = pkbf(v[8], v[9]);   w1.y = pkbf(v[10], v[11]);
        w1.z = pkbf(v[12], v[13]); w1.w = pkbf(v[14], v[15]);

        char* dst = ws + WS_A + (size_t)b * SUBT_B + c * 16;
        const int g0 = kq >> 3;
        *reinterpret_cast<uint4*>(dst + g0 * 2048) = w0;
        *reinterpret_cast<uint4*>(dst + (g0 + 1) * 2048) = w1;
    }
}

// ---------------- pass 2: MFMA GEMM, direct + split-chunk blocks ------------
__global__ __launch_bounds__(256) void trimm_split_kernel(
    const char* __restrict__ ws, float* __restrict__ C,
    float* __restrict__ part) {
    const int tid = threadIdx.x;

    int bi = 0, bj = 0, ch = 0;
    bool direct = false;
    {   // split region first (ids [0,772)), longest-L first; then direct
        int r = blockIdx.x;
        int L = 32;
        bool found = false;
        for (; L >= 9; --L) {
            const int cpt = (L + 7) >> 3;
            const int cnt = (33 - L) * cpt;
            if (r < cnt) { bi = r / cpt; ch = r - bi * cpt; found = true; break; }
            r -= cnt;
        }
        if (!found) {
            for (L = 8;; --L) {
                const int cnt = 33 - L;
                if (r < cnt) { bi = r; ch = 0; direct = true; break; }
                r -= cnt;
            }
        }
        bj = bi + L - 1;
    }

    const int row0 = bi * 128;
    const int col0 = bj * 128;
    const int kstart = row0 + ch * 1024;
    const int kend = min(col0 + 128, kstart + 1024);
    const int nt = (kend - kstart) >> 5;         // 4..32 BK=32 steps
    const int kt0 = kstart >> 5;

    const char* asub = ws + (size_t)(offA(bi) + kt0 - 4 * bi) * SUBT_B;
    const char* bsub = ws + WS_A + (size_t)(offB(bj) + kt0) * SUBT_B;

    __shared__ __align__(16) char lds[3][2][SUBT_B];   // 48 KB, 3 blocks/CU

    f32x4 acc[4][4];
    const f32x4 fz = {0.f, 0.f, 0.f, 0.f};
#pragma unroll
    for (int m = 0; m < 4; ++m)
#pragma unroll
        for (int n = 0; n < 4; ++n) acc[m][n] = fz;

    const int wv = tid >> 6;
    const int wr = (wv >> 1) * 64;
    const int wc = (wv & 1) * 64;
    const int lane = tid & 63;
    const int fr = lane & 15;
    const int gof = (lane >> 4) * 2048;

    auto stage = [&](int buf, int t) {           // 4 gll16 per wave
#pragma unroll
        for (int q = 0; q < 2; ++q) {
            const int c = wv * 2 + q;
            gll16(asub + (size_t)t * SUBT_B + c * 1024 + lane * 16,
                  &lds[buf][0][c * 1024]);
            gll16(bsub + (size_t)t * SUBT_B + c * 1024 + lane * 16,
                  &lds[buf][1][c * 1024]);
        }
    };
    auto compute = [&](int buf) {
        const char* A_ = &lds[buf][0][0];
        const char* B_ = &lds[buf][1][0];
        short8 af[4], bf[4];
#pragma unroll
        for (int m = 0; m < 4; ++m)
            af[m] = *reinterpret_cast<const short8*>(
                A_ + gof + (wr + m * 16 + fr) * 16);
#pragma unroll
        for (int n = 0; n < 4; ++n)
            bf[n] = *reinterpret_cast<const short8*>(
                B_ + gof + (wc + n * 16 + fr) * 16);
#pragma unroll
        for (int m = 0; m < 4; ++m)
#pragma unroll
            for (int n = 0; n < 4; ++n)
                acc[m][n] = __builtin_amdgcn_mfma_f32_16x16x32_bf16(
                    af[m], bf[n], acc[m][n], 0, 0, 0);
    };

    stage(0, 0);
    if (nt > 1) stage(1, 1);
    for (int t = 0; t < nt; ++t) {
        if (t + 1 < nt)
            asm volatile("s_waitcnt vmcnt(4)" ::: "memory");
        else
            asm volatile("s_waitcnt vmcnt(0)" ::: "memory");
        __builtin_amdgcn_s_barrier();
        if (t + 2 < nt) stage((t + 2) % 3, t + 2);
        compute(t % 3);
    }

    if (direct) {
        // ---- direct masked store (full tile incl. zeros) ----
#pragma unroll
        for (int m = 0; m < 4; ++m) {
            const int rbase = row0 + wr + m * 16 + (lane >> 4) * 4;
#pragma unroll
            for (int n = 0; n < 4; ++n) {
                const int col = col0 + wc + n * 16 + fr;
#pragma unroll
                for (int r = 0; r < 4; ++r) {
                    const int row = rbase + r;
                    C[(size_t)row * NDIM + col] =
                        (row <= col) ? acc[m][n][r] : 0.f;
                }
            }
        }
    } else {
        // ---- partial store to ws slot = blockIdx.x (plain, no atomics) ----
        float* po = part + (size_t)blockIdx.x * PART_F;
#pragma unroll
        for (int m = 0; m < 4; ++m) {
            const int rloc = wr + m * 16 + (lane >> 4) * 4;
#pragma unroll
            for (int n = 0; n < 4; ++n) {
                const int cloc = wc + n * 16 + fr;
#pragma unroll
                for (int r = 0; r < 4; ++r)
                    po[(size_t)(rloc + r) * 128 + cloc] = acc[m][n][r];
            }
        }
    }
}

// ---------------- pass 3: sum partials -> C (split tiles only) --------------
__global__ __launch_bounds__(256) void reduce_kernel(
    const float* __restrict__ part, float* __restrict__ C) {
    const int t = threadIdx.x;
    int bi = 0, L = 32, slot0 = 0, cpt = 4;
    {
        int r = blockIdx.x, sbase = 0;
        for (;;) {
            cpt = (L + 7) >> 3;
            const int cnt = 33 - L;
            if (r < cnt) { bi = r; slot0 = sbase + r * cpt; break; }
            sbase += cnt * cpt;
            r -= cnt;
            --L;
        }
    }
    const int bj = bi + L - 1;          // bj >= bi+8 -> strictly upper tile
    const int row0 = bi * 128;
    const int col0 = bj * 128;

#pragma unroll
    for (int j = 0; j < 16; ++j) {
        const int e4 = t + 256 * j;      // float4 index 0..4095
        f32x4 s = *reinterpret_cast<const f32x4*>(
            part + (size_t)slot0 * PART_F + e4 * 4);
        for (int c = 1; c < cpt; ++c) {
            const f32x4 v = *reinterpret_cast<const f32x4*>(
                part + (size_t)(slot0 + c) * PART_F + e4 * 4);
            s += v;
        }
        const int rr = e4 >> 5;
        const int cc = (e4 & 31) * 4;
        *reinterpret_cast<f32x4*>(
            &C[(size_t)(row0 + rr) * NDIM + col0 + cc]) = s;
    }
}

// ---------------- mid path: R12 main (528 tiles, no partials) ---------------
__global__ __launch_bounds__(256) void trimm_whole_kernel(
    const char* __restrict__ ws, float* __restrict__ C) {
    const int tid = threadIdx.x;
    int bi, bj;
    {
        int r = blockIdx.x, L = NBLK;
        while (r >= NBLK + 1 - L) { r -= NBLK + 1 - L; --L; }
        bi = r;
        bj = bi + L - 1;
    }
    const int row0 = bi * 128;
    const int col0 = bj * 128;
    const int nt = (col0 + 128 - row0) >> 5;

    const char* asub = ws + (size_t)offA(bi) * SUBT_B;
    const char* bsub = ws + WS_A + (size_t)(offB(bj) + 4 * bi) * SUBT_B;

    __shared__ __align__(16) char lds[3][2][SUBT_B];
    f32x4 acc[4][4];
    const f32x4 fz = {0.f, 0.f, 0.f, 0.f};
#pragma unroll
    for (int m = 0; m < 4; ++m)
#pragma unroll
        for (int n = 0; n < 4; ++n) acc[m][n] = fz;

    const int wv = tid >> 6;
    const int wr = (wv >> 1) * 64;
    const int wc = (wv & 1) * 64;
    const int lane = tid & 63;
    const int fr = lane & 15;
    const int gof = (lane >> 4) * 2048;

    auto stage = [&](int buf, int t) {
#pragma unroll
        for (int q = 0; q < 2; ++q) {
            const int c = wv * 2 + q;
            gll16(asub + (size_t)t * SUBT_B + c * 1024 + lane * 16,
                  &lds[buf][0][c * 1024]);
            gll16(bsub + (size_t)t * SUBT_B + c * 1024 + lane * 16,
                  &lds[buf][1][c * 1024]);
        }
    };
    auto compute = [&](int buf) {
        const char* A_ = &lds[buf][0][0];
        const char* B_ = &lds[buf][1][0];
        short8 af[4], bf[4];
#pragma unroll
        for (int m = 0; m < 4; ++m)
            af[m] = *reinterpret_cast<const short8*>(
                A_ + gof + (wr + m * 16 + fr) * 16);
#pragma unroll
        for (int n = 0; n < 4; ++n)
            bf[n] = *reinterpret_cast<const short8*>(
                B_ + gof + (wc + n * 16 + fr) * 16);
#pragma unroll
        for (int m = 0; m < 4; ++m)
#pragma unroll
            for (int n = 0; n < 4; ++n)
                acc[m][n] = __builtin_amdgcn_mfma_f32_16x16x32_bf16(
                    af[m], bf[n], acc[m][n], 0, 0, 0);
    };

    stage(0, 0);
    if (nt > 1) stage(1, 1);
    for (int t = 0; t < nt; ++t) {
        if (t + 1 < nt)
            asm volatile("s_waitcnt vmcnt(4)" ::: "memory");
        else
            asm volatile("s_waitcnt vmcnt(0)" ::: "memory");
        __builtin_amdgcn_s_barrier();
        if (t + 2 < nt) stage((t + 2) % 3, t + 2);
        compute(t % 3);
    }
#pragma unroll
    for (int m = 0; m < 4; ++m) {
        const int rbase = row0 + wr + m * 16 + (lane >> 4) * 4;
#pragma unroll
        for (int n = 0; n < 4; ++n) {
            const int col = col0 + wc + n * 16 + fr;
#pragma unroll
            for (int r = 0; r < 4; ++r) {
                const int row = rbase + r;
                C[(size_t)row * NDIM + col] = (row <= col) ? acc[m][n][r] : 0.f;
            }
        }
    }
}

// ---------------- fallback (proven R3 kernel, no workspace) ----------------
#define FLSTR 80
__device__ __forceinline__ int floff(int row, int kb) { return row * FLSTR + kb; }

__global__ __launch_bounds__(256) void trimm_fallback_kernel(
    const float* __restrict__ A, const float* __restrict__ B,
    float* __restrict__ C) {
    const int tid = threadIdx.x;
    const int id = blockIdx.x;
    int bi, bj;
    if (id >= 528) {
        int r = id - 528;
        int p = 1;
        while (r >= p) { r -= p; ++p; }
        bi = p; bj = r;
        const size_t base = (size_t)bi * 128 * NDIM + (size_t)bj * 128;
        const float4 z = make_float4(0.f, 0.f, 0.f, 0.f);
#pragma unroll
        for (int t = 0; t < 16; ++t) {
            const int f = tid + 256 * t;
            *reinterpret_cast<float4*>(
                &C[base + (size_t)(f >> 5) * NDIM + (f & 31) * 4]) = z;
        }
        return;
    }
    {
        int r = id, L = NBLK;
        while (r >= NBLK + 1 - L) { r -= NBLK + 1 - L; --L; }
        bi = r; bj = bi + L - 1;
    }
    const int row0 = bi * 128, col0 = bj * 128;
    __shared__ __align__(16) char lAs[128 * FLSTR];
    __shared__ __align__(16) char lBs[128 * FLSTR];
    f32x4 acc[4][4];
    const f32x4 fz = {0.f, 0.f, 0.f, 0.f};
#pragma unroll
    for (int m = 0; m < 4; ++m)
#pragma unroll
        for (int n = 0; n < 4; ++n) acc[m][n] = fz;
    const int wv = tid >> 6, wr = (wv >> 1) * 64, wc = (wv & 1) * 64;
    const int lane = tid & 63, fr = lane & 15, kb = (lane >> 4) * 16;
    const int bn = tid & 127, bkh = (tid >> 7) * 16;
    const int kendf = col0 + 128;
    for (int kt = row0; kt < kendf; kt += 32) {
        __syncthreads();
#pragma unroll
        for (int j = 0; j < 4; ++j) {
            const int f = tid + 256 * j;
            const int rr = f >> 3, kq = (f & 7) * 4;
            const float4 v = *reinterpret_cast<const float4*>(
                &A[(size_t)(row0 + rr) * NDIM + kt + kq]);
            uint2 w;
            w.x = pkbf(v.x, v.y); w.y = pkbf(v.z, v.w);
            *reinterpret_cast<uint2*>(lAs + floff(rr, kq * 2)) = w;
        }
        {
            float tv[16];
#pragma unroll
            for (int kk = 0; kk < 16; ++kk)
                tv[kk] = B[(size_t)(kt + bkh + kk) * NDIM + col0 + bn];
            uint4 w0, w1;
            w0.x = pkbf(tv[0], tv[1]);   w0.y = pkbf(tv[2], tv[3]);
            w0.z = pkbf(tv[4], tv[5]);   w0.w = pkbf(tv[6], tv[7]);
            w1.x = pkbf(tv[8], tv[9]);   w1.y = pkbf(tv[10], tv[11]);
            w1.z = pkbf(tv[12], tv[13]); w1.w = pkbf(tv[14], tv[15]);
            *reinterpret_cast<uint4*>(lBs + floff(bn, bkh * 2)) = w0;
            *reinterpret_cast<uint4*>(lBs + floff(bn, bkh * 2 + 16)) = w1;
        }
        __syncthreads();
        short8 af[4], bf[4];
#pragma unroll
        for (int m = 0; m < 4; ++m)
            af[m] = *reinterpret_cast<const short8*>(
                lAs + floff(wr + m * 16 + fr, kb));
#pragma unroll
        for (int n = 0; n < 4; ++n)
            bf[n] = *reinterpret_cast<const short8*>(
                lBs + floff(wc + n * 16 + fr, kb));
#pragma unroll
        for (int m = 0; m < 4; ++m)
#pragma unroll
            for (int n = 0; n < 4; ++n)
                acc[m][n] = __builtin_amdgcn_mfma_f32_16x16x32_bf16(
                    af[m], bf[n], acc[m][n], 0, 0, 0);
    }
#pragma unroll
    for (int m = 0; m < 4; ++m) {
        const int rbase = row0 + wr + m * 16 + (lane >> 4) * 4;
#pragma unroll
        for (int n = 0; n < 4; ++n) {
            const int col = col0 + wc + n * 16 + fr;
#pragma unroll
            for (int r = 0; r < 4; ++r) {
                const int row = rbase + r;
                C[(size_t)row * NDIM + col] = (row <= col) ? acc[m][n][r] : 0.f;
            }
        }
    }
}

extern "C" void kernel_launch(void* const* d_in, const int* in_sizes, int n_in,
                              void* d_out, int out_size, void* d_ws,
                              size_t ws_size, hipStream_t stream) {
    const float* A = (const float*)d_in[0];
    const float* B = (const float*)d_in[1];
    float* C = (float*)d_out;
    if (ws_size >= WS_FULL) {
        char* ws = (char*)d_ws;
        float* part = (float*)(ws + WS_TOTAL);
        prep_kernel<<<dim3(NZERO + 2 * NSUBT), dim3(256), 0, stream>>>(A, B, C, ws);
        trimm_split_kernel<<<dim3(NMAIN), dim3(256), 0, stream>>>(ws, C, part);
        reduce_kernel<<<dim3(NRED), dim3(256), 0, stream>>>(part, C);
    } else if (ws_size >= WS_TOTAL) {
        char* ws = (char*)d_ws;
        prep_kernel<<<dim3(NZERO + 2 * NSUBT), dim3(256), 0, stream>>>(A, B, C, ws);
        trimm_whole_kernel<<<dim3(528), dim3(256), 0, stream>>>(ws, C);
    } else {
        trimm_fallback_kernel<<<dim3(1024), dim3(256), 0, stream>>>(A, B, C);
    }
}